// Round 1
// baseline (350.245 us; speedup 1.0000x reference)
//
#include <hip/hip_runtime.h>
#include <hip/hip_bf16.h>
#include <math.h>

// Problem constants
#define BB 4
#define LL 512
#define DD 768
#define HH 12
#define DH 64
#define RR 128
#define BL (BB*LL)      // 2048
#define D3 (3*DD)       // 2304
#define NC 8            // chunks over L
#define CT 64           // chunk length
#define PI_F 3.14159265358979323846f

__device__ __forceinline__ float sigmoidf_(float x) { return 1.0f / (1.0f + expf(-x)); }
__device__ __forceinline__ float elu1f_(float x)    { return x > 0.0f ? x + 1.0f : expf(x); }

// ---------------------------------------------------------------------------
// Kernel 1: row layernorm over D=768  (x -> x_norm)
// ---------------------------------------------------------------------------
__global__ __launch_bounds__(256) void ln_row_kernel(const float* __restrict__ x,
                                                     const float* __restrict__ g,
                                                     const float* __restrict__ b,
                                                     float* __restrict__ xn) {
    int row = blockIdx.x;
    int t = threadIdx.x;
    int w = t >> 6;
    int lane = t & 63;
    float v[3];
    float s = 0.f, s2 = 0.f;
#pragma unroll
    for (int i = 0; i < 3; i++) {
        v[i] = x[(size_t)row * DD + t + i * 256];
        s += v[i];
        s2 += v[i] * v[i];
    }
#pragma unroll
    for (int off = 1; off < 64; off <<= 1) {
        s  += __shfl_xor(s, off);
        s2 += __shfl_xor(s2, off);
    }
    __shared__ float rs[4], rs2[4];
    if (lane == 0) { rs[w] = s; rs2[w] = s2; }
    __syncthreads();
    s  = rs[0] + rs[1] + rs[2] + rs[3];
    s2 = rs2[0] + rs2[1] + rs2[2] + rs2[3];
    float mu = s * (1.0f / DD);
    float var = s2 * (1.0f / DD) - mu * mu;
    float rstd = rsqrtf(var + 1e-5f);
#pragma unroll
    for (int i = 0; i < 3; i++) {
        int col = t + i * 256;
        xn[(size_t)row * DD + col] = (v[i] - mu) * rstd * g[col] + b[col];
    }
}

// ---------------------------------------------------------------------------
// Kernel 2: tiled fp32 GEMM  C[M,N] = A[M,K] @ B[K,N] (+bias | silu)
// ACT=0: +bias     ACT=1: silu, no bias
// Requires M%64==0, N%64==0, K%16==0
// ---------------------------------------------------------------------------
template <int ACT>
__global__ __launch_bounds__(256) void gemm_kernel(const float* __restrict__ A,
                                                   const float* __restrict__ Bm,
                                                   const float* __restrict__ bias,
                                                   float* __restrict__ C,
                                                   int M, int N, int K) {
    __shared__ float As[16][64];
    __shared__ float Bs[16][64];
    int t = threadIdx.x;
    int tx = t & 15, ty = t >> 4;
    int bm = blockIdx.y * 64, bn = blockIdx.x * 64;
    float acc[4][4] = {};
    int arow = t >> 2, acg = t & 3;
    int brow = t >> 4, bcg = t & 15;
    for (int k0 = 0; k0 < K; k0 += 16) {
        float4 av = *(const float4*)&A[(size_t)(bm + arow) * K + k0 + acg * 4];
        As[acg * 4 + 0][arow] = av.x;
        As[acg * 4 + 1][arow] = av.y;
        As[acg * 4 + 2][arow] = av.z;
        As[acg * 4 + 3][arow] = av.w;
        *(float4*)&Bs[brow][bcg * 4] = *(const float4*)&Bm[(size_t)(k0 + brow) * N + bn + bcg * 4];
        __syncthreads();
#pragma unroll
        for (int kk = 0; kk < 16; kk++) {
            float a[4], bb[4];
            *(float4*)a  = *(const float4*)&As[kk][ty * 4];
            *(float4*)bb = *(const float4*)&Bs[kk][tx * 4];
#pragma unroll
            for (int i = 0; i < 4; i++)
#pragma unroll
                for (int j = 0; j < 4; j++)
                    acc[i][j] += a[i] * bb[j];
        }
        __syncthreads();
    }
#pragma unroll
    for (int i = 0; i < 4; i++) {
        int row = bm + ty * 4 + i;
#pragma unroll
        for (int j = 0; j < 4; j++) {
            int col = bn + tx * 4 + j;
            float v = acc[i][j];
            if (ACT == 0) v += bias[col];
            else          v = v * sigmoidf_(v);  // silu
            C[(size_t)row * N + col] = v;
        }
    }
}

// ---------------------------------------------------------------------------
// Kernel 3: gate params: params = h1[BL,128] @ Wb2[128,60]; gate math
// block = 256 threads = 4 rows x 64 lanes
// ---------------------------------------------------------------------------
__global__ __launch_bounds__(256) void gate_kernel(const float* __restrict__ h1,
                                                   const float* __restrict__ Wb2,
                                                   const float* __restrict__ temperature,
                                                   float* __restrict__ gate_ws,
                                                   float* __restrict__ gate_out) {
    __shared__ float w2s[RR * 60];   // 30 KB
    __shared__ float h1s[4][RR];
    __shared__ float ps[4][60];
    int t = threadIdx.x;
    for (int i = t; i < RR * 60; i += 256) w2s[i] = Wb2[i];
    int rr = t >> 6, lane = t & 63;
    int row = blockIdx.x * 4 + rr;
    h1s[rr][lane]      = h1[(size_t)row * RR + lane];
    h1s[rr][64 + lane] = h1[(size_t)row * RR + 64 + lane];
    __syncthreads();
    if (lane < 60) {
        float acc = 0.f;
#pragma unroll 8
        for (int k = 0; k < RR; k++) acc += h1s[rr][k] * w2s[k * 60 + lane];
        ps[rr][lane] = acc;
    }
    __syncthreads();
    if (lane < HH) {
        float p0 = ps[rr][lane * 5 + 0];
        float p1 = ps[rr][lane * 5 + 1];
        float p2 = ps[rr][lane * 5 + 2];
        float p3 = ps[rr][lane * 5 + 3];
        float temp = fminf(fmaxf(temperature[0], 0.1f), 2.0f);
        float sa = sigmoidf_(p0);
        float sp = tanhf(p1) * PI_F;
        float ca = sigmoidf_(p2);
        float cp = tanhf(p3) * PI_F;
        float itf = tanhf(sa * ca * cosf(sp - cp)) * temp;
        float gt = sigmoidf_(itf);
        size_t gi = (size_t)row * HH + lane;
        gate_ws[gi] = gt;
        gate_out[gi] = gt;
    }
}

// ---------------------------------------------------------------------------
// Kernel 4 (pass A): per-chunk local state S_local = sum_j w_j k_j v_j^T, z_local
// grid = B*H*NC blocks; thread t: e = t&63, g = t>>6 (wave id), owns S[g*16+i][e]
// ---------------------------------------------------------------------------
__global__ __launch_bounds__(256) void passA_kernel(const float* __restrict__ qkv,
                                                    const float* __restrict__ gate,
                                                    float* __restrict__ states) {
    int blk = blockIdx.x;
    int c = blk % NC, bh = blk / NC;
    int b = bh / HH, h = bh % HH;
    __shared__ float Ks[CT][DH];
    __shared__ float Vs[CT][DH];
    __shared__ float wsm[CT];
    int t = threadIdx.x;
#pragma unroll
    for (int i = 0; i < 4; i++) {
        int fid = i * 256 + t;      // 0..1023
        int j = fid >> 4, f = fid & 15;
        size_t row = (size_t)b * LL + c * CT + j;
        float4 k4 = *(const float4*)&qkv[row * D3 + DD + h * DH + f * 4];
        float4 v4 = *(const float4*)&qkv[row * D3 + 2 * DD + h * DH + f * 4];
        Ks[j][f * 4 + 0] = elu1f_(k4.x);
        Ks[j][f * 4 + 1] = elu1f_(k4.y);
        Ks[j][f * 4 + 2] = elu1f_(k4.z);
        Ks[j][f * 4 + 3] = elu1f_(k4.w);
        *(float4*)&Vs[j][f * 4] = v4;
    }
    if (t < CT) wsm[t] = 1.0f + gate[((size_t)b * LL + c * CT + t) * HH + h];
    __syncthreads();
    int e = t & 63, g = t >> 6;
    float S[16] = {};
    for (int j = 0; j < CT; j++) {
        float vw = Vs[j][e] * wsm[j];
#pragma unroll
        for (int i = 0; i < 16; i++) S[i] += Ks[j][g * 16 + i] * vw;
    }
    float* st = states + (size_t)(bh * NC + c) * 4160;
#pragma unroll
    for (int i = 0; i < 16; i++) st[(g * 16 + i) * 64 + e] = S[i];
    if (g == 0) {
        float z = 0.f;
        for (int j = 0; j < CT; j++) z += Ks[j][e];
        st[4096 + e] = z;
    }
}

// ---------------------------------------------------------------------------
// Kernel 5 (pass B): exclusive prefix over chunks (in place)
// ---------------------------------------------------------------------------
__global__ __launch_bounds__(256) void passB_kernel(float* __restrict__ states) {
    int bh = blockIdx.x;
    int t = threadIdx.x;
    float* st = states + (size_t)bh * NC * 4160;
    for (int base = 0; base < 4160; base += 256) {
        int idx = base + t;
        if (idx < 4160) {
            float acc = 0.f;
#pragma unroll
            for (int c = 0; c < NC; c++) {
                float tmp = st[(size_t)c * 4160 + idx];
                st[(size_t)c * 4160 + idx] = acc;
                acc += tmp;
            }
        }
    }
}

// ---------------------------------------------------------------------------
// Kernel 6 (pass C): replay chunk with state, produce out = num/den (pre-LN)
// thread t: e = t>>2, g = t&3  (g in low lane bits -> intra-wave shfl reduce)
// ---------------------------------------------------------------------------
__global__ __launch_bounds__(256) void passC_kernel(const float* __restrict__ qkv,
                                                    const float* __restrict__ gate,
                                                    const float* __restrict__ states,
                                                    float* __restrict__ attn) {
    int blk = blockIdx.x;
    int c = blk % NC, bh = blk / NC;
    int b = bh / HH, h = bh % HH;
    __shared__ float Qs[CT][DH];
    __shared__ float Ks[CT][DH];
    __shared__ float Vs[CT][DH];
    __shared__ float wsm[CT];
    int t = threadIdx.x;
#pragma unroll
    for (int i = 0; i < 4; i++) {
        int fid = i * 256 + t;
        int j = fid >> 4, f = fid & 15;
        size_t row = (size_t)b * LL + c * CT + j;
        float4 q4 = *(const float4*)&qkv[row * D3 + h * DH + f * 4];
        float4 k4 = *(const float4*)&qkv[row * D3 + DD + h * DH + f * 4];
        float4 v4 = *(const float4*)&qkv[row * D3 + 2 * DD + h * DH + f * 4];
        Qs[j][f * 4 + 0] = elu1f_(q4.x);
        Qs[j][f * 4 + 1] = elu1f_(q4.y);
        Qs[j][f * 4 + 2] = elu1f_(q4.z);
        Qs[j][f * 4 + 3] = elu1f_(q4.w);
        Ks[j][f * 4 + 0] = elu1f_(k4.x);
        Ks[j][f * 4 + 1] = elu1f_(k4.y);
        Ks[j][f * 4 + 2] = elu1f_(k4.z);
        Ks[j][f * 4 + 3] = elu1f_(k4.w);
        *(float4*)&Vs[j][f * 4] = v4;
    }
    if (t < CT) wsm[t] = 1.0f + gate[((size_t)b * LL + c * CT + t) * HH + h];
    __syncthreads();
    int e = t >> 2, g = t & 3;
    const float* st = states + (size_t)(bh * NC + c) * 4160;
    float S[16], z[16];
#pragma unroll
    for (int i = 0; i < 16; i++) {
        S[i] = st[(g * 16 + i) * 64 + e];
        z[i] = st[4096 + g * 16 + i];
    }
    for (int j = 0; j < CT; j++) {
        float vw = Vs[j][e] * wsm[j];
        float num = 0.f, den = 0.f;
#pragma unroll
        for (int i = 0; i < 16; i++) {
            float kk = Ks[j][g * 16 + i];
            float qq = Qs[j][g * 16 + i];
            S[i] += kk * vw;   // inclusive update before use
            z[i] += kk;
            num += qq * S[i];
            den += qq * z[i];
        }
        num += __shfl_xor(num, 1);
        num += __shfl_xor(num, 2);
        den += __shfl_xor(den, 1);
        den += __shfl_xor(den, 2);
        if (g == 0) {
            size_t row = (size_t)b * LL + c * CT + j;
            attn[row * DD + h * DH + e] = num / (den + 1e-6f);
        }
    }
}

// ---------------------------------------------------------------------------
// Kernel 7: per-head layernorm over DH=64 (in place), one wave per head-row
// ---------------------------------------------------------------------------
__global__ __launch_bounds__(256) void ln_head_kernel(float* __restrict__ attn,
                                                      const float* __restrict__ mg,
                                                      const float* __restrict__ mb) {
    int w = threadIdx.x >> 6, lane = threadIdx.x & 63;
    size_t r = (size_t)blockIdx.x * 4 + w;   // row over B*L*H
    size_t base = r * DH + lane;
    float v = attn[base];
    float s = v, s2 = v * v;
#pragma unroll
    for (int off = 1; off < 64; off <<= 1) {
        s  += __shfl_xor(s, off);
        s2 += __shfl_xor(s2, off);
    }
    float mu = s * (1.0f / DH);
    float var = s2 * (1.0f / DH) - mu * mu;
    float rstd = rsqrtf(var + 1e-5f);
    attn[base] = (v - mu) * rstd * mg[lane] + mb[lane];
}

// ---------------------------------------------------------------------------
extern "C" void kernel_launch(void* const* d_in, const int* in_sizes, int n_in,
                              void* d_out, int out_size, void* d_ws, size_t ws_size,
                              hipStream_t stream) {
    const float* x    = (const float*)d_in[0];
    const float* Wqkv = (const float*)d_in[1];
    const float* bqkv = (const float*)d_in[2];
    const float* Wb1  = (const float*)d_in[3];
    const float* Wb2  = (const float*)d_in[4];
    const float* temperature = (const float*)d_in[5];
    const float* Wproj = (const float*)d_in[6];
    const float* bproj = (const float*)d_in[7];
    const float* ln_g = (const float*)d_in[8];
    const float* ln_b = (const float*)d_in[9];
    const float* mn_g = (const float*)d_in[10];
    const float* mn_b = (const float*)d_in[11];

    float* out0     = (float*)d_out;                    // (B,L,D)
    float* gate_out = out0 + (size_t)BL * DD;           // (B,L,H)

    float* ws = (float*)d_ws;
    float* xn     = ws;                                 // BL*D      = 1,572,864
    float* qkv    = xn + (size_t)BL * DD;               // BL*3D     = 4,718,592
    float* h1     = qkv + (size_t)BL * D3;              // BL*R      =   262,144
    float* gate   = h1 + (size_t)BL * RR;               // BL*H      =    24,576
    float* states = gate + (size_t)BL * HH;             // 48*8*4160 = 1,597,440
    float* attn   = states + (size_t)BB * HH * NC * 4160; // BL*D    = 1,572,864
    // total ~9.75M floats = 39 MB

    // 1. x_norm
    ln_row_kernel<<<BL, 256, 0, stream>>>(x, ln_g, ln_b, xn);
    // 2. qkv = x_norm @ Wqkv + bqkv
    gemm_kernel<0><<<dim3(D3 / 64, BL / 64), 256, 0, stream>>>(xn, Wqkv, bqkv, qkv, BL, D3, DD);
    // 3. h1 = silu(x @ Wb1)   (raw x!)
    gemm_kernel<1><<<dim3(RR / 64, BL / 64), 256, 0, stream>>>(x, Wb1, nullptr, h1, BL, RR, DD);
    // 4. gate
    gate_kernel<<<BL / 4, 256, 0, stream>>>(h1, Wb2, temperature, gate, gate_out);
    // 5-7. chunked linear-attention scan
    passA_kernel<<<BB * HH * NC, 256, 0, stream>>>(qkv, gate, states);
    passB_kernel<<<BB * HH, 256, 0, stream>>>(states);
    passC_kernel<<<BB * HH * NC, 256, 0, stream>>>(qkv, gate, states, attn);
    // 8. per-head layernorm
    ln_head_kernel<<<(BL * HH) / 4, 256, 0, stream>>>(attn, mn_g, mn_b);
    // 9. out = attn @ Wproj + bproj
    gemm_kernel<0><<<dim3(DD / 64, BL / 64), 256, 0, stream>>>(attn, Wproj, bproj, out0, BL, DD, DD);
}

// Round 2
// 228.511 us; speedup vs baseline: 1.5327x; 1.5327x over previous
//
#include <hip/hip_runtime.h>
#include <hip/hip_bf16.h>
#include <math.h>

// Problem constants
#define BB 4
#define LL 512
#define DD 768
#define HH 12
#define DH 64
#define RR 128
#define BL (BB*LL)      // 2048
#define D3 (3*DD)       // 2304
#define NC 8            // chunks over L
#define CT 64           // chunk length
#define PI_F 3.14159265358979323846f

typedef short bf16x8 __attribute__((ext_vector_type(8)));
typedef float f32x4 __attribute__((ext_vector_type(4)));

__device__ __forceinline__ float sigmoidf_(float x) { return 1.0f / (1.0f + expf(-x)); }
__device__ __forceinline__ float elu1f_(float x)    { return x > 0.0f ? x + 1.0f : expf(x); }
__device__ __forceinline__ unsigned short f2bf(float f) {
    unsigned u = __float_as_uint(f);
    unsigned r = u + 0x7FFF + ((u >> 16) & 1);
    return (unsigned short)(r >> 16);
}

// ---------------------------------------------------------------------------
// Kernel 1: row layernorm over D=768  (x -> x_norm, bf16 output)
// ---------------------------------------------------------------------------
__global__ __launch_bounds__(256) void ln_row_kernel(const float* __restrict__ x,
                                                     const float* __restrict__ g,
                                                     const float* __restrict__ b,
                                                     unsigned short* __restrict__ xn) {
    int row = blockIdx.x;
    int t = threadIdx.x;
    int w = t >> 6;
    int lane = t & 63;
    float v[3];
    float s = 0.f, s2 = 0.f;
#pragma unroll
    for (int i = 0; i < 3; i++) {
        v[i] = x[(size_t)row * DD + t + i * 256];
        s += v[i];
        s2 += v[i] * v[i];
    }
#pragma unroll
    for (int off = 1; off < 64; off <<= 1) {
        s  += __shfl_xor(s, off);
        s2 += __shfl_xor(s2, off);
    }
    __shared__ float rs[4], rs2[4];
    if (lane == 0) { rs[w] = s; rs2[w] = s2; }
    __syncthreads();
    s  = rs[0] + rs[1] + rs[2] + rs[3];
    s2 = rs2[0] + rs2[1] + rs2[2] + rs2[3];
    float mu = s * (1.0f / DD);
    float var = s2 * (1.0f / DD) - mu * mu;
    float rstd = rsqrtf(var + 1e-5f);
#pragma unroll
    for (int i = 0; i < 3; i++) {
        int col = t + i * 256;
        xn[(size_t)row * DD + col] = f2bf((v[i] - mu) * rstd * g[col] + b[col]);
    }
}

// ---------------------------------------------------------------------------
// Kernel 1b: elementwise f32 -> bf16
// ---------------------------------------------------------------------------
__global__ __launch_bounds__(256) void convert_bf16_kernel(const float* __restrict__ in,
                                                           unsigned short* __restrict__ out) {
    int i = (blockIdx.x * 256 + threadIdx.x) * 4;
    float4 v = *(const float4*)&in[i];
    ushort4 o;
    o.x = f2bf(v.x); o.y = f2bf(v.y); o.z = f2bf(v.z); o.w = f2bf(v.w);
    *(ushort4*)&out[i] = o;
}

// ---------------------------------------------------------------------------
// Kernel 1c: transpose f32 [K][N] -> bf16 [N][K]
// grid (N/32, K/32), 256 threads
// ---------------------------------------------------------------------------
__global__ __launch_bounds__(256) void transpose_bf16_kernel(const float* __restrict__ in,
                                                             unsigned short* __restrict__ out,
                                                             int K, int N) {
    __shared__ float tile[32][33];
    int n0 = blockIdx.x * 32, k0 = blockIdx.y * 32;
    int tx = threadIdx.x & 31, ty = threadIdx.x >> 5;   // ty 0..7
#pragma unroll
    for (int i = 0; i < 4; i++)
        tile[ty + i * 8][tx] = in[(size_t)(k0 + ty + i * 8) * N + n0 + tx];
    __syncthreads();
#pragma unroll
    for (int i = 0; i < 4; i++)
        out[(size_t)(n0 + ty + i * 8) * K + k0 + tx] = f2bf(tile[tx][ty + i * 8]);
}

// ---------------------------------------------------------------------------
// Kernel 2: bf16 MFMA GEMM  C[M,N] = A[M,K] @ B[K,N] (+bias | silu), fp32 out
// A: bf16 [M][K] row-major.  Bt: bf16 [N][K] (B transposed).
// 128x128 tile, BK=32, 4 waves (2x2), each wave 64x64 via 4x4 of 16x16x32.
// Requires M%128==0, N%128==0, K%32==0.
// ---------------------------------------------------------------------------
template <int ACT>
__global__ __launch_bounds__(256) void gemm_bf16_kernel(const unsigned short* __restrict__ A,
                                                        const unsigned short* __restrict__ Bt,
                                                        const float* __restrict__ bias,
                                                        float* __restrict__ C,
                                                        int M, int N, int K) {
    constexpr int LDT = 40;  // padded LDS stride (elements): 2-way-only bank conflicts
    __shared__ __align__(16) unsigned short As[128 * LDT];
    __shared__ __align__(16) unsigned short Bs[128 * LDT];
    int t = threadIdx.x;
    int lane = t & 63, w = t >> 6;
    int wrow = w >> 1, wcol = w & 1;
    int quad = lane >> 4, l16 = lane & 15;
    int bm = blockIdx.y * 128, bn = blockIdx.x * 128;

    f32x4 acc[4][4];
#pragma unroll
    for (int i = 0; i < 4; i++)
#pragma unroll
        for (int j = 0; j < 4; j++)
            acc[i][j] = (f32x4){0.f, 0.f, 0.f, 0.f};

    int srow = t >> 2, scg = t & 3;  // staging: 64 rows/iter, 4x8 bf16 per row

    for (int k0 = 0; k0 < K; k0 += 32) {
        __syncthreads();
#pragma unroll
        for (int i = 0; i < 2; i++) {
            int row = srow + i * 64;
            int4 av = *(const int4*)&A[(size_t)(bm + row) * K + k0 + scg * 8];
            *(int4*)&As[row * LDT + scg * 8] = av;
            int4 bv = *(const int4*)&Bt[(size_t)(bn + row) * K + k0 + scg * 8];
            *(int4*)&Bs[row * LDT + scg * 8] = bv;
        }
        __syncthreads();
        bf16x8 af[4], bf[4];
#pragma unroll
        for (int mi = 0; mi < 4; mi++)
            af[mi] = *(const bf16x8*)&As[(wrow * 64 + mi * 16 + l16) * LDT + quad * 8];
#pragma unroll
        for (int ni = 0; ni < 4; ni++)
            bf[ni] = *(const bf16x8*)&Bs[(wcol * 64 + ni * 16 + l16) * LDT + quad * 8];
#pragma unroll
        for (int mi = 0; mi < 4; mi++)
#pragma unroll
            for (int ni = 0; ni < 4; ni++)
                acc[mi][ni] = __builtin_amdgcn_mfma_f32_16x16x32_bf16(af[mi], bf[ni], acc[mi][ni], 0, 0, 0);
    }

#pragma unroll
    for (int mi = 0; mi < 4; mi++) {
#pragma unroll
        for (int r = 0; r < 4; r++) {
            int row = bm + wrow * 64 + mi * 16 + quad * 4 + r;
#pragma unroll
            for (int ni = 0; ni < 4; ni++) {
                int col = bn + wcol * 64 + ni * 16 + l16;
                float v = acc[mi][ni][r];
                if (ACT == 0) v += bias[col];
                else          v = v * sigmoidf_(v);  // silu
                C[(size_t)row * N + col] = v;
            }
        }
    }
}

// ---------------------------------------------------------------------------
// Kernel 3: gate params: params = h1[BL,128] @ Wb2[128,60]; gate math
// ---------------------------------------------------------------------------
__global__ __launch_bounds__(256) void gate_kernel(const float* __restrict__ h1,
                                                   const float* __restrict__ Wb2,
                                                   const float* __restrict__ temperature,
                                                   float* __restrict__ gate_ws,
                                                   float* __restrict__ gate_out) {
    __shared__ float w2s[RR * 60];
    __shared__ float h1s[4][RR];
    __shared__ float ps[4][60];
    int t = threadIdx.x;
    for (int i = t; i < RR * 60; i += 256) w2s[i] = Wb2[i];
    int rr = t >> 6, lane = t & 63;
    int row = blockIdx.x * 4 + rr;
    h1s[rr][lane]      = h1[(size_t)row * RR + lane];
    h1s[rr][64 + lane] = h1[(size_t)row * RR + 64 + lane];
    __syncthreads();
    if (lane < 60) {
        float acc = 0.f;
#pragma unroll 8
        for (int k = 0; k < RR; k++) acc += h1s[rr][k] * w2s[k * 60 + lane];
        ps[rr][lane] = acc;
    }
    __syncthreads();
    if (lane < HH) {
        float p0 = ps[rr][lane * 5 + 0];
        float p1 = ps[rr][lane * 5 + 1];
        float p2 = ps[rr][lane * 5 + 2];
        float p3 = ps[rr][lane * 5 + 3];
        float temp = fminf(fmaxf(temperature[0], 0.1f), 2.0f);
        float sa = sigmoidf_(p0);
        float sp = tanhf(p1) * PI_F;
        float ca = sigmoidf_(p2);
        float cp = tanhf(p3) * PI_F;
        float itf = tanhf(sa * ca * cosf(sp - cp)) * temp;
        float gt = sigmoidf_(itf);
        size_t gi = (size_t)row * HH + lane;
        gate_ws[gi] = gt;
        gate_out[gi] = gt;
    }
}

// ---------------------------------------------------------------------------
// Kernel 4 (pass A): per-chunk local state S_local
// ---------------------------------------------------------------------------
__global__ __launch_bounds__(256) void passA_kernel(const float* __restrict__ qkv,
                                                    const float* __restrict__ gate,
                                                    float* __restrict__ states) {
    int blk = blockIdx.x;
    int c = blk % NC, bh = blk / NC;
    int b = bh / HH, h = bh % HH;
    __shared__ float Ks[CT][DH];
    __shared__ float Vs[CT][DH];
    __shared__ float wsm[CT];
    int t = threadIdx.x;
#pragma unroll
    for (int i = 0; i < 4; i++) {
        int fid = i * 256 + t;
        int j = fid >> 4, f = fid & 15;
        size_t row = (size_t)b * LL + c * CT + j;
        float4 k4 = *(const float4*)&qkv[row * D3 + DD + h * DH + f * 4];
        float4 v4 = *(const float4*)&qkv[row * D3 + 2 * DD + h * DH + f * 4];
        Ks[j][f * 4 + 0] = elu1f_(k4.x);
        Ks[j][f * 4 + 1] = elu1f_(k4.y);
        Ks[j][f * 4 + 2] = elu1f_(k4.z);
        Ks[j][f * 4 + 3] = elu1f_(k4.w);
        *(float4*)&Vs[j][f * 4] = v4;
    }
    if (t < CT) wsm[t] = 1.0f + gate[((size_t)b * LL + c * CT + t) * HH + h];
    __syncthreads();
    int e = t & 63, g = t >> 6;
    float S[16] = {};
    for (int j = 0; j < CT; j++) {
        float vw = Vs[j][e] * wsm[j];
#pragma unroll
        for (int i = 0; i < 16; i++) S[i] += Ks[j][g * 16 + i] * vw;
    }
    float* st = states + (size_t)(bh * NC + c) * 4160;
#pragma unroll
    for (int i = 0; i < 16; i++) st[(g * 16 + i) * 64 + e] = S[i];
    if (g == 0) {
        float z = 0.f;
        for (int j = 0; j < CT; j++) z += Ks[j][e];
        st[4096 + e] = z;
    }
}

// ---------------------------------------------------------------------------
// Kernel 5 (pass B): exclusive prefix over chunks (in place)
// ---------------------------------------------------------------------------
__global__ __launch_bounds__(256) void passB_kernel(float* __restrict__ states) {
    int bh = blockIdx.x;
    int t = threadIdx.x;
    float* st = states + (size_t)bh * NC * 4160;
    for (int base = 0; base < 4160; base += 256) {
        int idx = base + t;
        if (idx < 4160) {
            float acc = 0.f;
#pragma unroll
            for (int c = 0; c < NC; c++) {
                float tmp = st[(size_t)c * 4160 + idx];
                st[(size_t)c * 4160 + idx] = acc;
                acc += tmp;
            }
        }
    }
}

// ---------------------------------------------------------------------------
// Kernel 6 (pass C): replay chunk with state, out = num/den (pre-LN)
// ---------------------------------------------------------------------------
__global__ __launch_bounds__(256) void passC_kernel(const float* __restrict__ qkv,
                                                    const float* __restrict__ gate,
                                                    const float* __restrict__ states,
                                                    float* __restrict__ attn) {
    int blk = blockIdx.x;
    int c = blk % NC, bh = blk / NC;
    int b = bh / HH, h = bh % HH;
    __shared__ float Qs[CT][DH];
    __shared__ float Ks[CT][DH];
    __shared__ float Vs[CT][DH];
    __shared__ float wsm[CT];
    int t = threadIdx.x;
#pragma unroll
    for (int i = 0; i < 4; i++) {
        int fid = i * 256 + t;
        int j = fid >> 4, f = fid & 15;
        size_t row = (size_t)b * LL + c * CT + j;
        float4 q4 = *(const float4*)&qkv[row * D3 + h * DH + f * 4];
        float4 k4 = *(const float4*)&qkv[row * D3 + DD + h * DH + f * 4];
        float4 v4 = *(const float4*)&qkv[row * D3 + 2 * DD + h * DH + f * 4];
        Qs[j][f * 4 + 0] = elu1f_(q4.x);
        Qs[j][f * 4 + 1] = elu1f_(q4.y);
        Qs[j][f * 4 + 2] = elu1f_(q4.z);
        Qs[j][f * 4 + 3] = elu1f_(q4.w);
        Ks[j][f * 4 + 0] = elu1f_(k4.x);
        Ks[j][f * 4 + 1] = elu1f_(k4.y);
        Ks[j][f * 4 + 2] = elu1f_(k4.z);
        Ks[j][f * 4 + 3] = elu1f_(k4.w);
        *(float4*)&Vs[j][f * 4] = v4;
    }
    if (t < CT) wsm[t] = 1.0f + gate[((size_t)b * LL + c * CT + t) * HH + h];
    __syncthreads();
    int e = t >> 2, g = t & 3;
    const float* st = states + (size_t)(bh * NC + c) * 4160;
    float S[16], z[16];
#pragma unroll
    for (int i = 0; i < 16; i++) {
        S[i] = st[(g * 16 + i) * 64 + e];
        z[i] = st[4096 + g * 16 + i];
    }
    for (int j = 0; j < CT; j++) {
        float vw = Vs[j][e] * wsm[j];
        float num = 0.f, den = 0.f;
#pragma unroll
        for (int i = 0; i < 16; i++) {
            float kk = Ks[j][g * 16 + i];
            float qq = Qs[j][g * 16 + i];
            S[i] += kk * vw;
            z[i] += kk;
            num += qq * S[i];
            den += qq * z[i];
        }
        num += __shfl_xor(num, 1);
        num += __shfl_xor(num, 2);
        den += __shfl_xor(den, 1);
        den += __shfl_xor(den, 2);
        if (g == 0) {
            size_t row = (size_t)b * LL + c * CT + j;
            attn[row * DD + h * DH + e] = num / (den + 1e-6f);
        }
    }
}

// ---------------------------------------------------------------------------
// Kernel 7: per-head layernorm over DH=64, fp32 in -> bf16 out
// ---------------------------------------------------------------------------
__global__ __launch_bounds__(256) void ln_head_kernel(const float* __restrict__ attn,
                                                      const float* __restrict__ mg,
                                                      const float* __restrict__ mb,
                                                      unsigned short* __restrict__ attn_bf) {
    int w = threadIdx.x >> 6, lane = threadIdx.x & 63;
    size_t r = (size_t)blockIdx.x * 4 + w;
    size_t base = r * DH + lane;
    float v = attn[base];
    float s = v, s2 = v * v;
#pragma unroll
    for (int off = 1; off < 64; off <<= 1) {
        s  += __shfl_xor(s, off);
        s2 += __shfl_xor(s2, off);
    }
    float mu = s * (1.0f / DH);
    float var = s2 * (1.0f / DH) - mu * mu;
    float rstd = rsqrtf(var + 1e-5f);
    attn_bf[base] = f2bf((v - mu) * rstd * mg[lane] + mb[lane]);
}

// ---------------------------------------------------------------------------
extern "C" void kernel_launch(void* const* d_in, const int* in_sizes, int n_in,
                              void* d_out, int out_size, void* d_ws, size_t ws_size,
                              hipStream_t stream) {
    const float* x    = (const float*)d_in[0];
    const float* Wqkv = (const float*)d_in[1];
    const float* bqkv = (const float*)d_in[2];
    const float* Wb1  = (const float*)d_in[3];
    const float* Wb2  = (const float*)d_in[4];
    const float* temperature = (const float*)d_in[5];
    const float* Wproj = (const float*)d_in[6];
    const float* bproj = (const float*)d_in[7];
    const float* ln_g = (const float*)d_in[8];
    const float* ln_b = (const float*)d_in[9];
    const float* mn_g = (const float*)d_in[10];
    const float* mn_b = (const float*)d_in[11];

    float* out0     = (float*)d_out;                    // (B,L,D)
    float* gate_out = out0 + (size_t)BL * DD;           // (B,L,H)

    float* ws = (float*)d_ws;
    float* qkv    = ws;                                   // 4,718,592 f32
    float* h1     = qkv + (size_t)BL * D3;                //   262,144
    float* gate   = h1 + (size_t)BL * RR;                 //    24,576
    float* states = gate + (size_t)BL * HH;               // 1,597,440
    float* attn   = states + (size_t)BB * HH * NC * 4160; // 1,572,864
    unsigned short* xnbf  = (unsigned short*)(attn + (size_t)BL * DD); // 1,572,864 u16 (reused as attn_bf)
    unsigned short* xbf   = xnbf + (size_t)BL * DD;       // 1,572,864 u16
    unsigned short* wqkvt = xbf + (size_t)BL * DD;        // 1,769,472 u16
    unsigned short* wprojt= wqkvt + (size_t)D3 * DD;      //   589,824 u16
    unsigned short* wb1t  = wprojt + (size_t)DD * DD;     //    98,304 u16
    // total ~44 MB

    // 1. x_norm (bf16) + bf16 copy of raw x
    ln_row_kernel<<<BL, 256, 0, stream>>>(x, ln_g, ln_b, xnbf);
    convert_bf16_kernel<<<(BL * DD) / 1024, 256, 0, stream>>>(x, xbf);
    // weight transposes -> bf16 B^T
    transpose_bf16_kernel<<<dim3(D3 / 32, DD / 32), 256, 0, stream>>>(Wqkv, wqkvt, DD, D3);
    transpose_bf16_kernel<<<dim3(RR / 32, DD / 32), 256, 0, stream>>>(Wb1, wb1t, DD, RR);
    transpose_bf16_kernel<<<dim3(DD / 32, DD / 32), 256, 0, stream>>>(Wproj, wprojt, DD, DD);
    // 2. qkv = x_norm @ Wqkv + bqkv   (bf16 MFMA, fp32 out)
    gemm_bf16_kernel<0><<<dim3(D3 / 128, BL / 128), 256, 0, stream>>>(xnbf, wqkvt, bqkv, qkv, BL, D3, DD);
    // 3. h1 = silu(x @ Wb1)
    gemm_bf16_kernel<1><<<dim3(RR / 128, BL / 128), 256, 0, stream>>>(xbf, wb1t, nullptr, h1, BL, RR, DD);
    // 4. gate
    gate_kernel<<<BL / 4, 256, 0, stream>>>(h1, Wb2, temperature, gate, gate_out);
    // 5-7. chunked linear-attention scan
    passA_kernel<<<BB * HH * NC, 256, 0, stream>>>(qkv, gate, states);
    passB_kernel<<<BB * HH, 256, 0, stream>>>(states);
    passC_kernel<<<BB * HH * NC, 256, 0, stream>>>(qkv, gate, states, attn);
    // 8. per-head layernorm -> bf16 (reuse xnbf)
    ln_head_kernel<<<(BL * HH) / 4, 256, 0, stream>>>(attn, mn_g, mn_b, xnbf);
    // 9. out = attn @ Wproj + bproj
    gemm_bf16_kernel<0><<<dim3(DD / 128, BL / 128), 256, 0, stream>>>(xnbf, wprojt, bproj, out0, BL, DD, DD);
}